// Round 1
// baseline (971.767 us; speedup 1.0000x reference)
//
#include <hip/hip_runtime.h>
#include <math.h>

#define NN 50000
#define EE 800000
#define NPAIR 200000

typedef unsigned short u16;
typedef short short8v __attribute__((ext_vector_type(8)));
typedef float float16v __attribute__((ext_vector_type(16)));
typedef float float4v __attribute__((ext_vector_type(4)));

__device__ __forceinline__ float leaky(float x){ return x >= 0.f ? x : 0.2f*x; }

// bf16 round-to-nearest-even helpers for the hi/lo split
__device__ __forceinline__ u16 bfhi(float x){
  union{float f; unsigned u;} v; v.f = x;
  unsigned r = (v.u + 0x7FFFu + ((v.u >> 16) & 1u)) >> 16;
  return (u16)r;
}
__device__ __forceinline__ float bf2f(u16 h){
  union{unsigned u; float f;} v; v.u = ((unsigned)h) << 16; return v.f;
}
__device__ __forceinline__ void split2(float x, float y, unsigned &hp, unsigned &lp){
  u16 hx = bfhi(x), hy = bfhi(y);
  u16 lx = bfhi(x - bf2f(hx)), ly = bfhi(y - bf2f(hy));
  hp = (unsigned)hx | ((unsigned)hy << 16);
  lp = (unsigned)lx | ((unsigned)ly << 16);
}
#define MFMA_BF16 __builtin_amdgcn_mfma_f32_32x32x16_bf16
#define MFMA16    __builtin_amdgcn_mfma_f32_16x16x32_bf16

// ---------------- degree / norms / CSR build ----------------

__global__ void degree_kernel(const int* __restrict__ src, const int* __restrict__ dst,
                              int* cnt_out, int* cnt_in){
  int i = blockIdx.x*blockDim.x + threadIdx.x;
  if(i < EE){
    atomicAdd(&cnt_out[src[i]], 1);
    atomicAdd(&cnt_in[dst[i]], 1);
  }
}

__global__ void norm_kernel(const int* __restrict__ cnt_out, const int* __restrict__ cnt_in,
                            float* __restrict__ out_norm, float* __restrict__ in_norm){
  int i = blockIdx.x*blockDim.x + threadIdx.x;
  if(i < NN){
    int o = cnt_out[i]; if(o < 1) o = 1;
    int d = cnt_in[i];  if(d < 1) d = 1;
    out_norm[i] = 1.f/sqrtf((float)o);
    in_norm[i]  = 1.f/sqrtf((float)d);
  }
}

// single-block exclusive scan of cnt_in[NN] -> row_off[NN+1]
__global__ void scan_kernel(const int* __restrict__ cnt, int* __restrict__ row_off){
  const int T = 512;
  __shared__ int sums[T];
  int t = threadIdx.x;
  int chunk = (NN + T - 1)/T;
  int base = t*chunk;
  int hi = base + chunk; if(hi > NN) hi = NN;
  int s = 0;
  for(int i = base; i < hi; i++) s += cnt[i];
  sums[t] = s;
  __syncthreads();
  for(int off = 1; off < T; off <<= 1){
    int add = (t >= off) ? sums[t-off] : 0;
    __syncthreads();
    sums[t] += add;
    __syncthreads();
  }
  int run = sums[t] - s;
  for(int i = base; i < hi; i++){ row_off[i] = run; run += cnt[i]; }
  if(t == T-1) row_off[NN] = EE;
}

// ew2 = w * out_norm[src]: out_norm commutes with @W, folded into edge weight.
__global__ void bucket_kernel(const int* __restrict__ src, const int* __restrict__ dst,
                              const float* __restrict__ w, const float* __restrict__ out_norm,
                              const int* __restrict__ row_off,
                              int* fill, int* __restrict__ es, float* __restrict__ ew){
  int i = blockIdx.x*blockDim.x + threadIdx.x;
  if(i < EE){
    int d = dst[i];
    int s = src[i];
    int p = row_off[d] + atomicAdd(&fill[d], 1);
    es[p] = s;
    ew[p] = w[i] * out_norm[s];
  }
}

// W (K x M fp32, row-major) -> Wt_hi / Wt_lo (M x K bf16), transposed.
__global__ void wsplit_kernel(const float* __restrict__ W, int K, int M,
                              u16* __restrict__ Whi, u16* __restrict__ Wlo){
  int i = blockIdx.x*256 + threadIdx.x;     // i = m*K + k
  if(i < K*M){
    int m = i / K, k = i - m*K;
    float a = W[(size_t)k*M + m];
    u16 h = bfhi(a);
    Whi[i] = h;
    Wlo[i] = bfhi(a - bf2f(h));
  }
}

// P1 (160x80) -> P1t hi/lo [96 cols][160 k] (cols 80..95 zero);
// P2 (80x40)  -> P2t hi/lo [64 cols][80 k]  (cols 40..63 zero).
__global__ void psplit_kernel(const float* __restrict__ P1, const float* __restrict__ P2,
                              u16* __restrict__ P1th, u16* __restrict__ P1tl,
                              u16* __restrict__ P2th, u16* __restrict__ P2tl){
  int i = blockIdx.x*256 + threadIdx.x;
  if(i < 96*160){
    int c = i/160, k = i - c*160;
    float v = (c < 80) ? P1[k*80 + c] : 0.f;
    u16 h = bfhi(v);
    P1th[i] = h; P1tl[i] = bfhi(v - bf2f(h));
  }
  if(i < 64*80){
    int c = i/80, k = i - c*80;
    float v = (c < 40) ? P2[k*40 + c] : 0.f;
    u16 h = bfhi(v);
    P2th[i] = h; P2tl[i] = bfhi(v - bf2f(h));
  }
}

// ---------------- aggregation v3: one WAVE per node (R8, proven) -------------
template<int F, int MODE>
__global__ __launch_bounds__(256) void agg_kernel(
    const float* __restrict__ feat, const int* __restrict__ es,
    const float* __restrict__ ew, const int* __restrict__ row_off,
    const float* __restrict__ innorm, const float* __restrict__ bias,
    float* __restrict__ out){
  constexpr int F4 = F/4;
  int wid = threadIdx.x >> 6, lane = threadIdx.x & 63;
  int v = blockIdx.x*4 + wid;
  if(v >= NN || lane >= F4) return;
  int s = row_off[v], e = row_off[v+1];
  const float4* f4 = (const float4*)feat;
  float4 a0 = {0,0,0,0}, a1 = {0,0,0,0}, a2 = {0,0,0,0}, a3 = {0,0,0,0};
  int j = s;
  for(; j + 3 < e; j += 4){
    int   i0 = es[j],   i1 = es[j+1], i2 = es[j+2], i3 = es[j+3];
    float w0 = ew[j],   w1 = ew[j+1], w2 = ew[j+2], w3 = ew[j+3];
    float4 r0 = f4[(size_t)i0*F4 + lane];
    float4 r1 = f4[(size_t)i1*F4 + lane];
    float4 r2 = f4[(size_t)i2*F4 + lane];
    float4 r3 = f4[(size_t)i3*F4 + lane];
    a0.x += r0.x*w0; a0.y += r0.y*w0; a0.z += r0.z*w0; a0.w += r0.w*w0;
    a1.x += r1.x*w1; a1.y += r1.y*w1; a1.z += r1.z*w1; a1.w += r1.w*w1;
    a2.x += r2.x*w2; a2.y += r2.y*w2; a2.z += r2.z*w2; a2.w += r2.w*w2;
    a3.x += r3.x*w3; a3.y += r3.y*w3; a3.z += r3.z*w3; a3.w += r3.w*w3;
  }
  for(; j < e; j++){
    int idx = es[j]; float wt = ew[j];
    float4 r = f4[(size_t)idx*F4 + lane];
    a0.x += r.x*wt; a0.y += r.y*wt; a0.z += r.z*wt; a0.w += r.w*wt;
  }
  float4 r;
  r.x = (a0.x+a1.x)+(a2.x+a3.x);
  r.y = (a0.y+a1.y)+(a2.y+a3.y);
  r.z = (a0.z+a1.z)+(a2.z+a3.z);
  r.w = (a0.w+a1.w)+(a2.w+a3.w);
  if(MODE >= 1){
    float inm = innorm[v];
    float4 bb = *(const float4*)&bias[lane*4];
    r.x = r.x*inm + bb.x; r.y = r.y*inm + bb.y;
    r.z = r.z*inm + bb.z; r.w = r.w*inm + bb.w;
    if(MODE == 1){
      r.x = fmaxf(r.x, 0.f); r.y = fmaxf(r.y, 0.f);
      r.z = fmaxf(r.z, 0.f); r.w = fmaxf(r.w, 0.f);
    }
  }
  ((float4*)(out + (size_t)v*F))[lane] = r;
}

// ---------------- GEMM via MFMA bf16x2-split (R9, proven) --------------------
template<bool EPI>
__global__ __launch_bounds__(256) void gemm_mfma(
    const float* __restrict__ A, const u16* __restrict__ Bhi, const u16* __restrict__ Blo,
    float* __restrict__ C, int K, int M,
    const float* __restrict__ innorm, const float* __restrict__ bias){
  __shared__ u16 sAhi[128*40];
  __shared__ u16 sAlo[128*40];
  __shared__ u16 sBhi[128*40];
  __shared__ u16 sBlo[128*40];
  int tid = threadIdx.x;
  int row0 = blockIdx.x*128, col0 = blockIdx.y*128;
  int wv = tid >> 6, L = tid & 63;
  int wr = (wv >> 1)*64, wc = (wv & 1)*64;
  int srow = tid >> 1, skh = (tid & 1)*16;

  float16v acc[2][2];
  #pragma unroll
  for(int i = 0; i < 2; i++)
    #pragma unroll
    for(int j = 0; j < 2; j++)
      #pragma unroll
      for(int r = 0; r < 16; r++) acc[i][j][r] = 0.f;

  const float* Arow = A + (size_t)(row0 + srow)*K;
  bool av = (row0 + srow) < NN;
  bool bv = (col0 + srow) < M;
  const u16* bhsrc = Bhi + (size_t)(col0 + srow)*K;
  const u16* blsrc = Blo + (size_t)(col0 + srow)*K;
  const uint4 z4 = make_uint4(0,0,0,0);

  for(int k0 = 0; k0 < K; k0 += 32){
    float4 af0 = {0,0,0,0}, af1 = {0,0,0,0}, af2 = {0,0,0,0}, af3 = {0,0,0,0};
    if(av){
      af0 = *(const float4*)&Arow[k0 + skh];
      af1 = *(const float4*)&Arow[k0 + skh + 4];
      af2 = *(const float4*)&Arow[k0 + skh + 8];
      af3 = *(const float4*)&Arow[k0 + skh + 12];
    }
    uint4 bh0 = z4, bh1 = z4, bl0 = z4, bl1 = z4;
    if(bv){
      bh0 = *(const uint4*)&bhsrc[k0 + skh];
      bh1 = *(const uint4*)&bhsrc[k0 + skh + 8];
      bl0 = *(const uint4*)&blsrc[k0 + skh];
      bl1 = *(const uint4*)&blsrc[k0 + skh + 8];
    }
    unsigned h0,h1,h2,h3,h4,h5,h6,h7, l0,l1,l2,l3,l4,l5,l6,l7;
    split2(af0.x, af0.y, h0, l0); split2(af0.z, af0.w, h1, l1);
    split2(af1.x, af1.y, h2, l2); split2(af1.z, af1.w, h3, l3);
    split2(af2.x, af2.y, h4, l4); split2(af2.z, af2.w, h5, l5);
    split2(af3.x, af3.y, h6, l6); split2(af3.z, af3.w, h7, l7);
    __syncthreads();
    int sa = srow*40 + skh;
    *(uint4*)&sAhi[sa]     = make_uint4(h0,h1,h2,h3);
    *(uint4*)&sAhi[sa + 8] = make_uint4(h4,h5,h6,h7);
    *(uint4*)&sAlo[sa]     = make_uint4(l0,l1,l2,l3);
    *(uint4*)&sAlo[sa + 8] = make_uint4(l4,l5,l6,l7);
    *(uint4*)&sBhi[sa]     = bh0;
    *(uint4*)&sBhi[sa + 8] = bh1;
    *(uint4*)&sBlo[sa]     = bl0;
    *(uint4*)&sBlo[sa + 8] = bl1;
    __syncthreads();
    #pragma unroll
    for(int ks = 0; ks < 2; ks++){
      int ko = ks*16 + (L >> 5)*8;
      int ra0 = (wr + (L & 31))*40 + ko, ra1 = ra0 + 32*40;
      int rb0 = (wc + (L & 31))*40 + ko, rb1 = rb0 + 32*40;
      short8v ah0 = *(const short8v*)&sAhi[ra0];
      short8v ah1 = *(const short8v*)&sAhi[ra1];
      short8v al0 = *(const short8v*)&sAlo[ra0];
      short8v al1 = *(const short8v*)&sAlo[ra1];
      short8v bhf0 = *(const short8v*)&sBhi[rb0];
      short8v bhf1 = *(const short8v*)&sBhi[rb1];
      short8v blf0 = *(const short8v*)&sBlo[rb0];
      short8v blf1 = *(const short8v*)&sBlo[rb1];
      acc[0][0] = MFMA_BF16(ah0, bhf0, acc[0][0], 0,0,0);
      acc[0][0] = MFMA_BF16(al0, bhf0, acc[0][0], 0,0,0);
      acc[0][0] = MFMA_BF16(ah0, blf0, acc[0][0], 0,0,0);
      acc[0][1] = MFMA_BF16(ah0, bhf1, acc[0][1], 0,0,0);
      acc[0][1] = MFMA_BF16(al0, bhf1, acc[0][1], 0,0,0);
      acc[0][1] = MFMA_BF16(ah0, blf1, acc[0][1], 0,0,0);
      acc[1][0] = MFMA_BF16(ah1, bhf0, acc[1][0], 0,0,0);
      acc[1][0] = MFMA_BF16(al1, bhf0, acc[1][0], 0,0,0);
      acc[1][0] = MFMA_BF16(ah1, blf0, acc[1][0], 0,0,0);
      acc[1][1] = MFMA_BF16(ah1, bhf1, acc[1][1], 0,0,0);
      acc[1][1] = MFMA_BF16(al1, bhf1, acc[1][1], 0,0,0);
      acc[1][1] = MFMA_BF16(ah1, blf1, acc[1][1], 0,0,0);
    }
  }

  int cB = L & 31, rq = 4*(L >> 5);
  #pragma unroll
  for(int tr = 0; tr < 2; tr++){
    #pragma unroll
    for(int tc = 0; tc < 2; tc++){
      int c = col0 + wc + tc*32 + cB;
      if(c >= M) continue;
      #pragma unroll
      for(int reg = 0; reg < 16; reg++){
        int r = row0 + wr + tr*32 + (reg & 3) + 8*(reg >> 2) + rq;
        if(r >= NN) continue;
        float v = acc[tr][tc][reg];
        if(EPI) v = fmaxf(v*innorm[r] + bias[c], 0.f);
        C[(size_t)r*M + c] = v;
      }
    }
  }
}

// ---------------- predictor v7: 16x16x32 MFMA, zero-LDS stage 1 --------------
// Theory (R10): v6 was latency-bound (MfmaUtil 14.6%, VALU 30%, HBM 20%, Occ
// 31%): 20 barriers/block fencing P1-panel global->LDS staging, 6 jobs on 4
// waves, 52 KB LDS -> 3 blocks/CU, 5.6M LDS bank-conflict cycles. v7 re-tiles
// to 16x16x32: A-frag layout (row=L&15, k=(L>>4)*8+i) IS the gather layout, so
// z = h[a]*h[b] is computed+split to bf16 hi/lo entirely in registers (z LDS
// and all stage-1 barriers gone). B-frags read straight from L2-resident
// P1t/P2t (identical addresses for all 6250 blocks). 80 cols = 5x16 exact: no
// zero-pad waste, 5 balanced col-jobs per wave. Only y1 goes through LDS
// (22528 B, stride 88 u16 -> 44-dword rows, 2-way = free), ONE barrier total.
// Stage 2: K=80 as 2 full k-steps + tail step with lanes k>=80 zeroed via
// clamped address + zero A-frag. Stage 3: in-wave 16-lane butterfly per pair.
#define Y1STR 88
__global__ __launch_bounds__(256) void predictor_mfma(
    const float* __restrict__ h3,
    const int* __restrict__ ps, const int* __restrict__ pd,
    const int* __restrict__ ns, const int* __restrict__ nd,
    const u16* __restrict__ P1th, const u16* __restrict__ P1tl,
    const float* __restrict__ pb1,
    const u16* __restrict__ P2th, const u16* __restrict__ P2tl,
    const float* __restrict__ pb2,
    const float* __restrict__ P3, const float* __restrict__ pb3,
    float* __restrict__ out){
  __shared__ u16 y1h[64*Y1STR];        // 11264 B
  __shared__ u16 y1l[64*Y1STR];        // 11264 B

  int tid = threadIdx.x;
  int pair0 = blockIdx.x*64;           // grid = 400000/64 = 6250 exactly
  int w  = tid >> 6;                   // wave = pair-tile (16 pairs each)
  int L  = tid & 63;
  int lr = L & 15;                     // A row / B col within 16-tile
  int lg = L >> 4;                     // k-group 0..3
  int lk = lg*8;                       // k offset within 32-k step

  // ---- pair indices: lane's A-frag row is pair w*16+lr (matches gather) ----
  int q = pair0 + w*16 + lr;
  int ia, ib;
  if(q < NPAIR){ ia = ps[q]; ib = pd[q]; }
  else         { ia = ns[q-NPAIR]; ib = nd[q-NPAIR]; }
  const float4* ra = (const float4*)(h3 + (size_t)ia*160);
  const float4* rb = (const float4*)(h3 + (size_t)ib*160);

  // ---- stage 1: z @ P1, K=160 in 5 steps, A built in registers ----
  float4v acc1[5];
  #pragma unroll
  for(int c = 0; c < 5; c++) acc1[c] = (float4v){0.f,0.f,0.f,0.f};

  union U16B { unsigned u[4]; short8v s; };

  #pragma unroll
  for(int kt = 0; kt < 5; kt++){
    int k0 = kt*32;
    int g = (k0 + lk) >> 2;            // float4 index into the row
    float4 va0 = ra[g], va1 = ra[g+1];
    float4 vb0 = rb[g], vb1 = rb[g+1];
    U16B Ah, Al;
    split2(va0.x*vb0.x, va0.y*vb0.y, Ah.u[0], Al.u[0]);
    split2(va0.z*vb0.z, va0.w*vb0.w, Ah.u[1], Al.u[1]);
    split2(va1.x*vb1.x, va1.y*vb1.y, Ah.u[2], Al.u[2]);
    split2(va1.z*vb1.z, va1.w*vb1.w, Ah.u[3], Al.u[3]);
    #pragma unroll
    for(int ct = 0; ct < 5; ct++){
      int col = ct*16 + lr;            // < 80 always: no padding needed
      short8v bh = *(const short8v*)&P1th[col*160 + k0 + lk];
      short8v bl = *(const short8v*)&P1tl[col*160 + k0 + lk];
      acc1[ct] = MFMA16(Ah.s, bh, acc1[ct], 0,0,0);
      acc1[ct] = MFMA16(Al.s, bh, acc1[ct], 0,0,0);
      acc1[ct] = MFMA16(Ah.s, bl, acc1[ct], 0,0,0);
    }
  }

  // ---- y1 = leaky(acc1 + pb1) -> bf16 hi/lo in LDS [pair][col] ----
  // C/D 16x16 layout: col = lr, row(pair) = lg*4 + reg. 16 consecutive u16
  // per (lg,reg) lane-group = 8 banks, 2-way = free.
  #pragma unroll
  for(int ct = 0; ct < 5; ct++){
    int c = ct*16 + lr;
    float pb = pb1[c];
    #pragma unroll
    for(int r = 0; r < 4; r++){
      int p = w*16 + lg*4 + r;
      float v = leaky(acc1[ct][r] + pb);
      u16 hh = bfhi(v);
      y1h[p*Y1STR + c] = hh;
      y1l[p*Y1STR + c] = bfhi(v - bf2f(hh));
    }
  }
  __syncthreads();                     // the ONLY barrier

  // ---- stage 2: y1 @ P2, K=80 (2 full 32-k steps + zero-padded tail) ----
  float4v acc2[3];
  #pragma unroll
  for(int c = 0; c < 3; c++) acc2[c] = (float4v){0.f,0.f,0.f,0.f};

  const short8v z8 = {0,0,0,0,0,0,0,0};
  #pragma unroll
  for(int kt = 0; kt < 3; kt++){
    int k0 = kt*32;
    bool tail = (kt == 2) && (lg >= 2);      // k >= 80: contribute zero
    int kk = tail ? 64 : (k0 + lk);          // clamped in-bounds address
    short8v ah = *(const short8v*)&y1h[(w*16 + lr)*Y1STR + kk];
    short8v al = *(const short8v*)&y1l[(w*16 + lr)*Y1STR + kk];
    if(tail){ ah = z8; al = z8; }            // zero A => zero contribution
    #pragma unroll
    for(int ct = 0; ct < 3; ct++){
      int col = ct*16 + lr;                  // < 48; P2t cols 40..63 are zero
      short8v bh = *(const short8v*)&P2th[col*80 + kk];
      short8v bl = *(const short8v*)&P2tl[col*80 + kk];
      acc2[ct] = MFMA16(ah, bh, acc2[ct], 0,0,0);
      acc2[ct] = MFMA16(al, bh, acc2[ct], 0,0,0);
      acc2[ct] = MFMA16(ah, bl, acc2[ct], 0,0,0);
    }
  }

  // ---- stage 3: leaky(+pb2)*P3, butterfly over the 16-lane col group ----
  float pb3v = pb3[0];
  float pbc0 = 0.f, p3c0 = 0.f, pbc1 = 0.f, p3c1 = 0.f, pbc2 = 0.f, p3c2 = 0.f;
  { int c0 = lr, c1 = 16 + lr, c2 = 32 + lr;
    pbc0 = pb2[c0]; p3c0 = P3[c0];
    pbc1 = pb2[c1]; p3c1 = P3[c1];
    if(c2 < 40){ pbc2 = pb2[c2]; p3c2 = P3[c2]; } }
  #pragma unroll
  for(int r = 0; r < 4; r++){
    float v = leaky(acc2[0][r] + pbc0) * p3c0
            + leaky(acc2[1][r] + pbc1) * p3c1
            + leaky(acc2[2][r] + pbc2) * p3c2;
    v += __shfl_xor(v, 1);
    v += __shfl_xor(v, 2);
    v += __shfl_xor(v, 4);
    v += __shfl_xor(v, 8);
    if(lr == 0) out[pair0 + w*16 + lg*4 + r] = v + pb3v;
  }
}

// ---------------- launch ----------------

extern "C" void kernel_launch(void* const* d_in, const int* in_sizes, int n_in,
                              void* d_out, int out_size, void* d_ws, size_t ws_size,
                              hipStream_t stream) {
  const float* x  = (const float*)d_in[0];
  const float* w  = (const float*)d_in[1];
  const int* src  = (const int*)d_in[2];
  const int* dst  = (const int*)d_in[3];
  const int* ps   = (const int*)d_in[4];
  const int* pd   = (const int*)d_in[5];
  const int* ns   = (const int*)d_in[6];
  const int* nd   = (const int*)d_in[7];
  const float* W1 = (const float*)d_in[8];  const float* b1  = (const float*)d_in[9];
  const float* W2 = (const float*)d_in[10]; const float* b2  = (const float*)d_in[11];
  const float* W3 = (const float*)d_in[12]; const float* b3  = (const float*)d_in[13];
  const float* P1 = (const float*)d_in[14]; const float* pb1 = (const float*)d_in[15];
  const float* P2 = (const float*)d_in[16]; const float* pb2 = (const float*)d_in[17];
  const float* P3 = (const float*)d_in[18]; const float* pb3 = (const float*)d_in[19];
  float* out = (float*)d_out;

  char* p = (char*)d_ws;
  auto alloc = [&](size_t bytes)->char*{
    char* r = p; p += (bytes + 255) & ~(size_t)255; return r;
  };
  int*   cnt_out = (int*)  alloc(NN*4);          // these three must stay contiguous
  int*   cnt_in  = (int*)  alloc(NN*4);          // (zeroed with one memset)
  int*   fill    = (int*)  alloc(NN*4);
  int*   row_off = (int*)  alloc((NN+1)*4);
  float* out_nrm = (float*)alloc(NN*4);
  float* in_nrm  = (float*)alloc(NN*4);
  int*   es      = (int*)  alloc((size_t)EE*4);
  float* ew      = (float*)alloc((size_t)EE*4);
  u16*   w1h     = (u16*)  alloc(256*512*2);
  u16*   w1l     = (u16*)  alloc(256*512*2);
  u16*   w2h     = (u16*)  alloc(512*256*2);
  u16*   w2l     = (u16*)  alloc(512*256*2);
  u16*   w3h     = (u16*)  alloc(256*160*2);
  u16*   w3l     = (u16*)  alloc(256*160*2);
  u16*   p1th    = (u16*)  alloc(96*160*2);
  u16*   p1tl    = (u16*)  alloc(96*160*2);
  u16*   p2th    = (u16*)  alloc(64*80*2);
  u16*   p2tl    = (u16*)  alloc(64*80*2);
  float* bufA    = (float*)alloc((size_t)NN*512*4);  // h1 (N x 512)
  float* bufB    = (float*)alloc((size_t)NN*256*4);  // proj2 / proj3
  float* bufC    = (float*)alloc((size_t)NN*256*4);  // agg1 / h2

  size_t cntPad = (NN*4 + 255) & ~(size_t)255;
  hipMemsetAsync(cnt_out, 0, 3*cntPad, stream);

  degree_kernel<<<(EE+255)/256, 256, 0, stream>>>(src, dst, cnt_out, cnt_in);
  norm_kernel<<<(NN+255)/256, 256, 0, stream>>>(cnt_out, cnt_in, out_nrm, in_nrm);
  scan_kernel<<<1, 512, 0, stream>>>(cnt_in, row_off);
  bucket_kernel<<<(EE+255)/256, 256, 0, stream>>>(src, dst, w, out_nrm, row_off, fill, es, ew);
  wsplit_kernel<<<512, 256, 0, stream>>>(W1, 256, 512, w1h, w1l);
  wsplit_kernel<<<512, 256, 0, stream>>>(W2, 512, 256, w2h, w2l);
  wsplit_kernel<<<160, 256, 0, stream>>>(W3, 256, 160, w3h, w3l);
  psplit_kernel<<<60, 256, 0, stream>>>(P1, P2, p1th, p1tl, p2th, p2tl);

  int aggGrid = (NN + 3)/4;

  // layer 1: agg(x, ew2) @ W1, epilogue relu(*in_norm + b1)
  agg_kernel<256,0><<<aggGrid, 256, 0, stream>>>(x, es, ew, row_off, nullptr, nullptr, bufC);
  gemm_mfma<true><<<dim3(391,4), 256, 0, stream>>>(bufC, w1h, w1l, bufA, 256, 512, in_nrm, b1);

  // layer 2: agg(h1 @ W2, ew2), fused epilogue relu(*in_norm + b2)
  gemm_mfma<false><<<dim3(391,2), 256, 0, stream>>>(bufA, w2h, w2l, bufB, 512, 256, nullptr, nullptr);
  agg_kernel<256,1><<<aggGrid, 256, 0, stream>>>(bufB, es, ew, row_off, in_nrm, b2, bufC);

  // layer 3: agg(h2 @ W3, ew2), fused epilogue *in_norm + b3 -> d_out h region
  gemm_mfma<false><<<dim3(391,2), 256, 0, stream>>>(bufC, w3h, w3l, bufB, 256, 160, nullptr, nullptr);
  agg_kernel<160,2><<<aggGrid, 256, 0, stream>>>(bufB, es, ew, row_off, in_nrm, b3, out + 2*NPAIR);

  // predictor on pos+neg pairs (MFMA, v7: zero-LDS stage 1, one barrier)
  predictor_mfma<<<(2*NPAIR)/64, 256, 0, stream>>>(out + 2*NPAIR, ps, pd, ns, nd,
                                                   p1th, p1tl, pb1, p2th, p2tl, pb2,
                                                   P3, pb3, out);
}